// Round 1
// baseline (1116.965 us; speedup 1.0000x reference)
//
#include <hip/hip_runtime.h>
#include <math.h>

#define BB 4096
#define CC 50257
#define RAT_AVG_F 0.02f

// Output layout (floats): [0]=bootstrap, [1..4096]=s, [4097..8192]=zmax',
// [8193..12288]=max9d', [12289..16384]=max8d', [16385]=sum(1-s), [16386..20481]=s*max_9
#define OFF_S     1
#define OFF_ZMAX  (1 + BB)
#define OFF_M9D   (1 + 2*BB)
#define OFF_M8D   (1 + 3*BB)
#define OFF_CNT   (1 + 4*BB)
#define OFF_MAX9  (2 + 4*BB)

// merge one (value, index) candidate into a sorted top-3, JAX tie-break: lower index wins on equal value
__device__ __forceinline__ void merge1(float xv, int jj,
                                       float& v0, int& i0, float& v1, int& i1, float& v2, int& i2) {
    bool b0 = (xv > v0) || (xv == v0 && jj < i0);
    bool b1 = (xv > v1) || (xv == v1 && jj < i1);
    bool b2 = (xv > v2) || (xv == v2 && jj < i2);
    if (b0)      { v2 = v1; i2 = i1; v1 = v0; i1 = i0; v0 = xv; i0 = jj; }
    else if (b1) { v2 = v1; i2 = i1; v1 = xv; i1 = jj; }
    else if (b2) { v2 = xv; i2 = jj; }
}

// fast in-thread insert (indices strictly increasing within a thread, so strict > keeps first occurrence)
#define INS(xv_, jv_) do { float _x = (xv_); int _j = (jv_);            \
    if (_x > v0)      { v2 = v1; i2 = i1; v1 = v0; i1 = i0; v0 = _x; i0 = _j; } \
    else if (_x > v1) { v2 = v1; i2 = i1; v1 = _x; i1 = _j; }           \
    else if (_x > v2) { v2 = _x; i2 = _j; } } while (0)

__global__ __launch_bounds__(256) void row_stats_kernel(const float* __restrict__ y_pred,
                                                        const int* __restrict__ y,
                                                        float* __restrict__ out,
                                                        float* __restrict__ boot_ws) {
    const int row = blockIdx.x;
    const int tid = threadIdx.x;
    const float* rp = y_pred + (size_t)row * CC;

    float v0 = -INFINITY, v1 = -INFINITY, v2 = -INFINITY;
    int i0 = 0x7fffffff, i1 = 0x7fffffff, i2 = 0x7fffffff;
    float sum = 0.0f;

    const int C4 = CC / 4;  // 12564 float4s, 1 scalar tail (col 50256)
    const float4* rp4 = (const float4*)rp;
    for (int i = tid; i < C4; i += 256) {
        float4 x = rp4[i];
        int j = i << 2;
        sum += __expf(x.x) + __expf(x.y) + __expf(x.z) + __expf(x.w);
        INS(x.x, j); INS(x.y, j + 1); INS(x.z, j + 2); INS(x.w, j + 3);
    }
    if (tid == 0) {  // tail element
        float x = rp[CC - 1];
        sum += __expf(x);
        INS(x, CC - 1);
    }

    // wave (64-lane) reduction; only lane 0's result is consumed
    #pragma unroll
    for (int off = 32; off; off >>= 1) {
        float ov0 = __shfl_down(v0, off), ov1 = __shfl_down(v1, off), ov2 = __shfl_down(v2, off);
        int   oi0 = __shfl_down(i0, off), oi1 = __shfl_down(i1, off), oi2 = __shfl_down(i2, off);
        float os  = __shfl_down(sum, off);
        sum += os;
        merge1(ov0, oi0, v0, i0, v1, i1, v2, i2);
        merge1(ov1, oi1, v0, i0, v1, i1, v2, i2);
        merge1(ov2, oi2, v0, i0, v1, i1, v2, i2);
    }

    __shared__ float sv0[4], sv1[4], sv2[4], ssum[4];
    __shared__ int   si0[4], si1[4], si2[4];
    if ((tid & 63) == 0) {
        int w = tid >> 6;
        sv0[w] = v0; sv1[w] = v1; sv2[w] = v2; ssum[w] = sum;
        si0[w] = i0; si1[w] = i1; si2[w] = i2;
    }
    __syncthreads();

    if (tid == 0) {
        #pragma unroll
        for (int w = 1; w < 4; ++w) {
            sum += ssum[w];
            merge1(sv0[w], si0[w], v0, i0, v1, i1, v2, i2);
            merge1(sv1[w], si1[w], v0, i0, v1, i1, v2, i2);
            merge1(sv2[w], si2[w], v0, i0, v1, i1, v2, i2);
        }
        float S    = sum;
        float logS = __logf(S);
        int   lbl  = y[row];
        float xy   = rp[lbl];
        float fy   = __expf(xy) / S;
        bool  sflg = fy < RAT_AVG_F;

        float e0 = __expf(v0), e1 = __expf(v1), e2 = __expf(v2);
        float boot;
        if (sflg) {
            float inv_w = 1.0f / (e0 + e1 + e2);
            boot = -(e0 * (v0 - logS) + e1 * (v1 - logS) + e2 * (v2 - logS)) * inv_w;
        } else {
            boot = -(xy - logS);
        }
        boot_ws[row]        = boot;
        out[OFF_S + row]    = sflg ? 1.0f : 0.0f;
        out[OFF_ZMAX + row] = sflg ? (float)i0 : -1.0f;
        out[OFF_M9D + row]  = sflg ? (float)i1 : -1.0f;
        out[OFF_M8D + row]  = sflg ? (float)i2 : -1.0f;
        out[OFF_MAX9 + row] = sflg ? (e1 / S) : 0.0f;
    }
}

__global__ __launch_bounds__(256) void final_reduce_kernel(const float* __restrict__ boot_ws,
                                                           float* __restrict__ out) {
    const int tid = threadIdx.x;
    float bsum = 0.0f, csum = 0.0f;
    for (int i = tid; i < BB; i += 256) {
        bsum += boot_ws[i];
        csum += 1.0f - out[OFF_S + i];
    }
    #pragma unroll
    for (int off = 32; off; off >>= 1) {
        bsum += __shfl_down(bsum, off);
        csum += __shfl_down(csum, off);
    }
    __shared__ float sb[4], sc[4];
    if ((tid & 63) == 0) { sb[tid >> 6] = bsum; sc[tid >> 6] = csum; }
    __syncthreads();
    if (tid == 0) {
        float b = 0.0f, c = 0.0f;
        #pragma unroll
        for (int w = 0; w < 4; ++w) { b += sb[w]; c += sc[w]; }
        out[0]       = b / (float)BB;
        out[OFF_CNT] = c;
    }
}

extern "C" void kernel_launch(void* const* d_in, const int* in_sizes, int n_in,
                              void* d_out, int out_size, void* d_ws, size_t ws_size,
                              hipStream_t stream) {
    const float* y_pred = (const float*)d_in[0];
    const int*   y      = (const int*)d_in[1];
    float* out     = (float*)d_out;
    float* boot_ws = (float*)d_ws;  // BB floats

    row_stats_kernel<<<BB, 256, 0, stream>>>(y_pred, y, out, boot_ws);
    final_reduce_kernel<<<1, 256, 0, stream>>>(boot_ws, out);
}